// Round 9
// baseline (98.008 us; speedup 1.0000x reference)
//
#include <hip/hip_runtime.h>
#include <math.h>

// ---- config (mirrors reference) ----
#define SR_D        44100.0
#define N_SAMPLES   65536
#define BVOICES     256
#define TWO_PI_F    6.28318530717958647692f
#define TWO_PI_D    6.28318530717958647692528676655900577

#define TPB 256                      // threads per block
#define GROUPS 4                     // float4 groups per thread
#define GROUP_STRIDE (TPB * 4)       // 1024 samples between groups
#define SPB (GROUP_STRIDE * GROUPS)  // 4096 samples per block
#define BLOCKS_PER_ROW (N_SAMPLES / SPB)   // 16

__device__ __forceinline__ float fractf(float x) { return x - floorf(x); }

// Single fused kernel: per-voice constants are recomputed per block (all
// wave-uniform scalar math — row is derived from blockIdx, so the input
// loads lower to s_load broadcasts; the fp64 sin/cos chain is a few hundred
// cycles once per block, fully hidden across 4096 blocks). This removes the
// separate 1-block setup dispatch + the constant global round-trip.
// NOTE: log2 bounds MUST stay compiler-computed (log2(32.7)/log2(523.25)) —
// hand-typed literals off by 2e-4 caused the round-2..6 absmax=0.55 bug.
__global__ void __launch_bounds__(TPB)
amfm_fused_kernel(const float* __restrict__ th_am,
                  const float* __restrict__ th_fm,
                  const float* __restrict__ ph,
                  const float* __restrict__ ph_am,
                  const float* __restrict__ ph_fm,
                  const float* __restrict__ u_am_mi,
                  const float* __restrict__ u_fm_hz,
                  const float* __restrict__ u_f0_hz,
                  float* __restrict__ out) {
    const int bid  = blockIdx.x;
    const int row  = bid >> 4;                    // / BLOCKS_PER_ROW
    const int col0 = (bid & (BLOCKS_PER_ROW - 1)) * SPB;
    const int n0   = col0 + threadIdx.x * 4;      // group-0 start sample

    // ---- per-voice parameter mapping (f32, matches reference exp2 path) ----
    float am_hz = exp2f(th_am[row] * 4.0f - 1.0f);   // exp2(t*(3-(-1)) + (-1))
    float mi_am = u_am_mi[row];
    float mi_fm = th_fm[row];
    float fm_hz = exp2f(u_fm_hz[row] * 4.0f - 1.0f);
    const double l2lo = log2(32.7);
    const double l2hi = log2(523.25);
    float f0_hz = exp2f(u_f0_hz[row] * (float)(l2hi - l2lo) + (float)l2lo);

    // ---- closed-form cumsum constants (fp64, Dirichlet identity) ----
    // arg_rev[n] = Cc + c1*(n+1) - K4*cos(2pi*(th0rev + fmrev*n)),  h = pi*fm/SR
    double c1     = (double)f0_hz / SR_D;
    double h      = M_PI * (double)fm_hz / SR_D;
    double K4     = c1 * (double)mi_fm / (2.0 * sin(h));
    double a      = TWO_PI_D * (double)ph_fm[row];
    double Cc     = (double)ph[row] + K4 * cos(a - h);
    double th0rev = (a + h) / TWO_PI_D;
    double fmrev  = (double)fm_hz / SR_D;
    double amrev  = (double)am_hz / SR_D;

    const float c1f    = (float)c1;
    const float fmrevf = (float)fmrev;
    const float amrevf = (float)amrev;
    const float K4f    = (float)K4;
    const float halfmi = 0.5f * mi_am;
    const double g = (double)GROUP_STRIDE;
    const float c1k = (float)(g * c1    - floor(g * c1));
    const float fmk = (float)(g * fmrev - floor(g * fmrev));
    const float amk = (float)(g * amrev - floor(g * amrev));

    // ---- fp64 group-0 bases, reduced to [0,1) revolutions ----
    double db = Cc + c1 * (double)(n0 + 1);
    float carb = (float)(db - floor(db));
    double tb = th0rev + fmrev * (double)n0;
    float thb = (float)(tb - floor(tb));
    double ab = (double)ph_am[row] + amrev * (double)n0;
    float amb = (float)(ab - floor(ab));

    float* op = out + (size_t)row * N_SAMPLES + n0;

#pragma unroll
    for (int j = 0; j < GROUPS; ++j) {
        float r[4];
#pragma unroll
        for (int k = 0; k < 4; ++k) {
            const float kk = (float)k;
            // FM oscillator: cos(2pi*theta), theta in revolutions
            float th = fractf(fmaf(fmrevf, kk, thb));
            float cv = __cosf(TWO_PI_F * th);
            // carrier phase (closed-form cumsum), revolutions
            float ar = fmaf(-K4f, cv, fmaf(c1f, kk, carb));
            ar = fractf(ar);
            float s = __sinf(TWO_PI_F * ar);
            // AM envelope
            float am = fractf(fmaf(amrevf, kk, amb));
            float av = __sinf(TWO_PI_F * am);
            r[k] = s * fmaf(halfmi, av, 0.5f);    // 0.5*s*(1+mi*av)
        }
        reinterpret_cast<float4*>(op + j * GROUP_STRIDE)[0] =
            make_float4(r[0], r[1], r[2], r[3]);
        // advance group bases by fract(1024*step), stay in [0,1)
        carb = fractf(carb + c1k);
        thb  = fractf(thb + fmk);
        amb  = fractf(amb + amk);
    }
}

extern "C" void kernel_launch(void* const* d_in, const int* in_sizes, int n_in,
                              void* d_out, int out_size, void* d_ws, size_t ws_size,
                              hipStream_t stream) {
    const float* th_am  = (const float*)d_in[0];
    const float* th_fm  = (const float*)d_in[1];
    const float* ph     = (const float*)d_in[2];
    const float* ph_am  = (const float*)d_in[3];
    const float* ph_fm  = (const float*)d_in[4];
    const float* u_am   = (const float*)d_in[5];
    const float* u_fm   = (const float*)d_in[6];
    const float* u_f0   = (const float*)d_in[7];
    float* out = (float*)d_out;

    const int nblocks = BVOICES * BLOCKS_PER_ROW;   // 4096
    amfm_fused_kernel<<<nblocks, TPB, 0, stream>>>(th_am, th_fm, ph, ph_am,
                                                   ph_fm, u_am, u_fm, u_f0, out);
}